// Round 1
// baseline (2904.516 us; speedup 1.0000x reference)
//
#include <hip/hip_runtime.h>
#include <stdint.h>

#define N_INST 192
#define C_FEAT 256
#define HW 784        // 28*28
#define P_PTS 392
#define CS 256
#define HS 200
#define WSEM 304
#define SEM_HW (HS*WSEM)      // 60800
#define NROWS (N_INST*P_PTS)  // 75264

__device__ __forceinline__ float b2f(unsigned short u){
  union { float f; unsigned int i; } v; v.i = ((unsigned int)u) << 16; return v.f;
}
__device__ __forceinline__ unsigned short f2b(float f){
  union { float f; unsigned int i; } v; v.f = f;
  unsigned int r = v.i + 0x7FFFu + ((v.i >> 16) & 1u);  // RNE
  return (unsigned short)(r >> 16);
}

// ---------------------------------------------------------------------------
// K1: per-instance single-channel 1x1 conv (label-selected row of W_inst/W_det)
// f64 accumulation so top-k ordering matches the reference's ordering exactly.
__global__ __launch_bounds__(256) void k_preds(
    const float* __restrict__ feats, const int* __restrict__ labels,
    const float* __restrict__ Wi, const float* __restrict__ bi,
    const float* __restrict__ Wd, const float* __restrict__ bd,
    float* __restrict__ out0, float* __restrict__ out1){
  int n = blockIdx.x, tid = threadIdx.x;
  int lab = labels[n];
  const float* wirow = Wi + (size_t)lab*C_FEAT;
  const float* wdrow = Wd + (size_t)lab*C_FEAT;
  const float* base  = feats + (size_t)n*C_FEAT*HW;
  double ai0=0, ai1=0, ai2=0, ai3=0, ad0=0, ad1=0, ad2=0, ad3=0;
  for(int c=0;c<C_FEAT;c++){
    float wi = wirow[c], wd = wdrow[c];
    const float* row = base + (size_t)c*HW;
    float v0 = row[tid];
    float v1 = row[tid+256];
    float v2 = row[tid+512];                      // 255+512=767 < 784 always ok
    float v3 = (tid < HW-768) ? row[tid+768] : 0.f;
    ai0 += (double)wi*v0; ai1 += (double)wi*v1; ai2 += (double)wi*v2; ai3 += (double)wi*v3;
    ad0 += (double)wd*v0; ad1 += (double)wd*v1; ad2 += (double)wd*v2; ad3 += (double)wd*v3;
  }
  float bv_i = bi[lab], bv_d = bd[lab];
  float* o0 = out0 + (size_t)n*HW;
  float* o1 = out1 + (size_t)n*HW;
  o0[tid]     = (float)ai0 + bv_i;  o1[tid]     = (float)ad0 + bv_d;
  o0[tid+256] = (float)ai1 + bv_i;  o1[tid+256] = (float)ad1 + bv_d;
  o0[tid+512] = (float)ai2 + bv_i;  o1[tid+512] = (float)ad2 + bv_d;
  if(tid < HW-768){ o0[tid+768] = (float)ai3 + bv_i; o1[tid+768] = (float)ad3 + bv_d; }
}

// ---------------------------------------------------------------------------
// K2: exact top-392-of-784 per instance by rank counting (jax tie-break: lower
// index wins on equal values). Rank is a permutation 0..783 -> compaction free.
__global__ __launch_bounds__(256) void k_topk(const float* __restrict__ preds,
                                              int* __restrict__ points){
  __shared__ float v[HW];
  int n = blockIdx.x, tid = threadIdx.x;
  const float* src = preds + (size_t)n*HW;
  for(int i=tid;i<HW;i+=256) v[i]=src[i];
  __syncthreads();
  for(int i=tid;i<HW;i+=256){
    float vi = v[i]; int rank=0;
    for(int j=0;j<HW;j++){
      float vj = v[j];
      rank += (vj > vi) || (vj == vi && j < i);
    }
    if(rank < P_PTS) points[n*P_PTS + rank] = i;
  }
}

// ---------------------------------------------------------------------------
// K3: sem = relu(W_sem @ semantic_feat + b_sem), output bf16 NHWC (pixel-major,
// channel-contiguous). GEMM M=121600 (pixels), N=256, K=256. 128x64 tile.
__global__ __launch_bounds__(256) void k_sem(
    const float* __restrict__ feat, const float* __restrict__ Wsem,
    const float* __restrict__ bsem, unsigned short* __restrict__ sem_t){
  __shared__ float As[128][65];
  __shared__ float Bs[64][65];
  int pix0 = blockIdx.x * 128;     // 60800 % 128 == 0 -> never straddles batch
  int o0   = blockIdx.y * 64;
  int tid  = threadIdx.x;
  int b    = pix0 / SEM_HW;
  int sp0  = pix0 - b*SEM_HW;
  const float* fbase = feat + (size_t)b*CS*SEM_HW + sp0;
  float acc[8][4];
  #pragma unroll
  for(int i=0;i<8;i++){ acc[i][0]=0.f; acc[i][1]=0.f; acc[i][2]=0.f; acc[i][3]=0.f; }
  int ty = tid >> 4, tx = tid & 15;
  int lp4 = tid & 31, lcA = tid >> 5;   // A load: 4 consecutive pixels / thread
  int kk  = tid & 15, loB = tid >> 4;   // B load: float4 along K / thread
  for(int k0=0;k0<CS;k0+=64){
    __syncthreads();
    #pragma unroll
    for(int r=0;r<8;r++){
      int k = lcA + 8*r;
      float4 av = *(const float4*)(fbase + (size_t)(k0+k)*SEM_HW + 4*lp4);
      As[4*lp4+0][k]=av.x; As[4*lp4+1][k]=av.y; As[4*lp4+2][k]=av.z; As[4*lp4+3][k]=av.w;
    }
    #pragma unroll
    for(int r=0;r<4;r++){
      int o = loB + 16*r;
      float4 wv4 = *(const float4*)(Wsem + (size_t)(o0+o)*CS + k0 + 4*kk);
      Bs[o][4*kk+0]=wv4.x; Bs[o][4*kk+1]=wv4.y; Bs[o][4*kk+2]=wv4.z; Bs[o][4*kk+3]=wv4.w;
    }
    __syncthreads();
    for(int k=0;k<64;k++){
      float a[8], wv[4];
      #pragma unroll
      for(int j=0;j<8;j++) a[j] = As[ty*8+j][k];
      #pragma unroll
      for(int q=0;q<4;q++) wv[q] = Bs[tx*4+q][k];
      #pragma unroll
      for(int j=0;j<8;j++)
        #pragma unroll
        for(int q=0;q<4;q++) acc[j][q] += a[j]*wv[q];
    }
  }
  float bv[4];
  #pragma unroll
  for(int q=0;q<4;q++) bv[q] = bsem[o0 + tx*4 + q];
  #pragma unroll
  for(int j=0;j<8;j++){
    int pix = pix0 + ty*8 + j;
    unsigned short* dst = sem_t + (size_t)pix*CS + o0 + tx*4;
    ushort4 pk;
    pk.x = f2b(fmaxf(acc[j][0]+bv[0],0.f));
    pk.y = f2b(fmaxf(acc[j][1]+bv[1],0.f));
    pk.z = f2b(fmaxf(acc[j][2]+bv[2],0.f));
    pk.w = f2b(fmaxf(acc[j][3]+bv[3],0.f));
    *(ushort4*)dst = pk;
  }
}

// ---------------------------------------------------------------------------
// K4: bilinear-sample sem at ROI-mapped point locations (fine, cols 0..255) and
// gather coarse instance features (cols 256..511, written to BOTH X buffers).
// One 64-lane wave per point; lane covers 4 channels.
__global__ __launch_bounds__(256) void k_sample(
    const unsigned short* __restrict__ sem_t, const float* __restrict__ feats,
    const float* __restrict__ rois, const int* __restrict__ points,
    unsigned short* __restrict__ X0, unsigned short* __restrict__ X1){
  int gid  = blockIdx.x*4 + (threadIdx.x >> 6);
  int lane = threadIdx.x & 63;
  if(gid >= NROWS) return;
  int n   = gid / P_PTS;
  int idx = points[gid];
  int b = (int)rois[n*5+0];
  float rx1 = rois[n*5+1], ry1 = rois[n*5+2], rx2 = rois[n*5+3], ry2 = rois[n*5+4];
  const float wstep = 1.0f/28.0f;
  float xs = 0.5f*wstep + (float)(idx % 28) * wstep;
  float ys = 0.5f*wstep + (float)(idx / 28) * wstep;
  float sx = (rx1 + xs*(rx2-rx1))*0.25f - 0.5f;
  float sy = (ry1 + ys*(ry2-ry1))*0.25f - 0.5f;
  float x0f = floorf(sx), y0f = floorf(sy);
  int   x0i = (int)x0f,   y0i = (int)y0f;
  float wx1 = sx - x0f, wx0 = 1.f - wx1;
  float wy1 = sy - y0f, wy0 = 1.f - wy1;
  float f0=0.f, f1=0.f, f2=0.f, f3=0.f;
  #pragma unroll
  for(int cr=0; cr<4; ++cr){
    int dx = cr & 1, dy = cr >> 1;
    int xi = x0i + dx, yi = y0i + dy;
    float w = (dx ? wx1 : wx0) * (dy ? wy1 : wy0);
    if(xi >= 0 && xi < WSEM && yi >= 0 && yi < HS && w != 0.f){
      const unsigned short* srow = sem_t + ((size_t)(b*SEM_HW + yi*WSEM + xi))*CS + lane;
      f0 += w * b2f(srow[0]);
      f1 += w * b2f(srow[64]);
      f2 += w * b2f(srow[128]);
      f3 += w * b2f(srow[192]);
    }
  }
  size_t xrow = (size_t)gid * 512;
  X0[xrow + lane      ] = f2b(f0);
  X0[xrow + lane + 64 ] = f2b(f1);
  X0[xrow + lane + 128] = f2b(f2);
  X0[xrow + lane + 192] = f2b(f3);
  const float* fb = feats + (size_t)n*C_FEAT*HW + idx;
  #pragma unroll
  for(int q=0;q<4;q++){
    int c = lane + 64*q;
    unsigned short cv = f2b(fb[(size_t)c*HW]);
    X0[xrow + 256 + c] = cv;
    X1[xrow + 256 + c] = cv;
  }
}

// ---------------------------------------------------------------------------
// K5: point MLP layer: Xout[:,0:256] = act(W @ Xin[:,0:512] + b).
// GEMM M=75264, N=256, K=512; 128x64 tile, 8x4 microtile, fp32 accumulate.
__global__ __launch_bounds__(256) void k_mlp(
    const unsigned short* __restrict__ Xin, const float* __restrict__ Wf,
    const float* __restrict__ bf, unsigned short* __restrict__ Xout, int do_relu){
  __shared__ float As[128][65];
  __shared__ float Bs[64][65];
  int r0 = blockIdx.x * 128;
  int o0 = blockIdx.y * 64;
  int tid = threadIdx.x;
  float acc[8][4];
  #pragma unroll
  for(int i=0;i<8;i++){ acc[i][0]=0.f; acc[i][1]=0.f; acc[i][2]=0.f; acc[i][3]=0.f; }
  int ty = tid >> 4, tx = tid & 15;
  int kk = tid & 15, li = tid >> 4;   // load: ushort4/float4 along K
  for(int k0=0;k0<512;k0+=64){
    __syncthreads();
    #pragma unroll
    for(int r=0;r<8;r++){
      int i = li + 16*r;
      ushort4 xv = *(const ushort4*)(Xin + (size_t)(r0+i)*512 + k0 + 4*kk);
      As[i][4*kk+0]=b2f(xv.x); As[i][4*kk+1]=b2f(xv.y);
      As[i][4*kk+2]=b2f(xv.z); As[i][4*kk+3]=b2f(xv.w);
    }
    #pragma unroll
    for(int r=0;r<4;r++){
      int o = li + 16*r;
      float4 wv4 = *(const float4*)(Wf + (size_t)(o0+o)*512 + k0 + 4*kk);
      Bs[o][4*kk+0]=wv4.x; Bs[o][4*kk+1]=wv4.y; Bs[o][4*kk+2]=wv4.z; Bs[o][4*kk+3]=wv4.w;
    }
    __syncthreads();
    for(int k=0;k<64;k++){
      float a[8], wv[4];
      #pragma unroll
      for(int j=0;j<8;j++) a[j] = As[ty*8+j][k];
      #pragma unroll
      for(int q=0;q<4;q++) wv[q] = Bs[tx*4+q][k];
      #pragma unroll
      for(int j=0;j<8;j++)
        #pragma unroll
        for(int q=0;q<4;q++) acc[j][q] += a[j]*wv[q];
    }
  }
  float bv[4];
  #pragma unroll
  for(int q=0;q<4;q++) bv[q] = bf[o0 + tx*4 + q];
  #pragma unroll
  for(int j=0;j<8;j++){
    size_t row = (size_t)(r0 + ty*8 + j);
    unsigned short* dst = Xout + row*512 + o0 + tx*4;
    ushort4 pk;
    float v0 = acc[j][0]+bv[0], v1 = acc[j][1]+bv[1], v2 = acc[j][2]+bv[2], v3 = acc[j][3]+bv[3];
    if(do_relu){ v0=fmaxf(v0,0.f); v1=fmaxf(v1,0.f); v2=fmaxf(v2,0.f); v3=fmaxf(v3,0.f); }
    pk.x=f2b(v0); pk.y=f2b(v1); pk.z=f2b(v2); pk.w=f2b(v3);
    *(ushort4*)dst = pk;
  }
}

// ---------------------------------------------------------------------------
// K6a: refined = bf16(relu(instance_feats))  (base for scatter+upsample)
__global__ void k_refinit(const float* __restrict__ feats, unsigned short* __restrict__ refined){
  const size_t total = (size_t)N_INST*C_FEAT*HW/4;
  for(size_t i = (size_t)blockIdx.x*blockDim.x + threadIdx.x; i < total;
      i += (size_t)gridDim.x*blockDim.x){
    float4 v = ((const float4*)feats)[i];
    ushort4 pk;
    pk.x = f2b(fmaxf(v.x,0.f)); pk.y = f2b(fmaxf(v.y,0.f));
    pk.z = f2b(fmaxf(v.z,0.f)); pk.w = f2b(fmaxf(v.w,0.f));
    ((ushort4*)refined)[i] = pk;
  }
}

// K6b: scatter relu(fuse output) into refined at the selected points.
__global__ __launch_bounds__(256) void k_scatter(const unsigned short* __restrict__ X0,
    const int* __restrict__ points, unsigned short* __restrict__ refined){
  int n = blockIdx.x;
  for(int p = threadIdx.x; p < P_PTS; p += 256){
    int idx = points[n*P_PTS + p];
    size_t xrow = ((size_t)n*P_PTS + p) * 512;
    unsigned short* rb = refined + (size_t)n*C_FEAT*HW + idx;
    #pragma unroll 4
    for(int c4=0;c4<256;c4+=4){
      ushort4 xv = *(const ushort4*)(X0 + xrow + c4);
      rb[(size_t)(c4+0)*HW] = f2b(fmaxf(b2f(xv.x),0.f));
      rb[(size_t)(c4+1)*HW] = f2b(fmaxf(b2f(xv.y),0.f));
      rb[(size_t)(c4+2)*HW] = f2b(fmaxf(b2f(xv.z),0.f));
      rb[(size_t)(c4+3)*HW] = f2b(fmaxf(b2f(xv.w),0.f));
    }
  }
}

// ---------------------------------------------------------------------------
// K7: 2x bilinear upsample, jax.image.resize semantics (half-pixel, triangle
// kernel, edge-renormalized): s = o*0.5-0.25; out[0]=in[0]; out[55]=in[27].
__global__ __launch_bounds__(256) void k_upsample(const unsigned short* __restrict__ refined,
                                                  float* __restrict__ out2){
  const size_t total = (size_t)N_INST * C_FEAT * 56 * 14;   // 4 outputs / thread
  for(size_t t = (size_t)blockIdx.x*blockDim.x + threadIdx.x; t < total;
      t += (size_t)gridDim.x*blockDim.x){
    int xq = (int)(t % 14);
    size_t r1 = t / 14;
    int oy = (int)(r1 % 56);
    size_t nc = r1 / 56;
    const unsigned short* in = refined + nc * HW;
    float sy = oy*0.5f - 0.25f;
    int iy0 = (int)floorf(sy);
    float wy1 = sy - (float)iy0, wy0 = 1.f - wy1;
    int iy1 = iy0 + 1;
    if(iy0 < 0){ iy0 = 0; wy0 = 0.f; wy1 = 1.f; iy1 = 0; }
    if(iy1 > 27){ iy1 = 27; wy0 = 1.f; wy1 = 0.f; }
    const unsigned short* rp0 = in + iy0*28;
    const unsigned short* rp1 = in + iy1*28;
    float4 ov; float* op = (float*)&ov;
    #pragma unroll
    for(int tq=0;tq<4;tq++){
      int ox = xq*4 + tq;
      float sxx = ox*0.5f - 0.25f;
      int ix0 = (int)floorf(sxx);
      float wx1 = sxx - (float)ix0, wx0 = 1.f - wx1;
      int ix1 = ix0 + 1;
      if(ix0 < 0){ ix0 = 0; wx0 = 0.f; wx1 = 1.f; ix1 = 0; }
      if(ix1 > 27){ ix1 = 27; wx0 = 1.f; wx1 = 0.f; }
      float v = wy0*(wx0*b2f(rp0[ix0]) + wx1*b2f(rp0[ix1]))
              + wy1*(wx0*b2f(rp1[ix0]) + wx1*b2f(rp1[ix1]));
      op[tq] = fmaxf(v, 0.f);
    }
    *(float4*)(out2 + nc*3136 + (size_t)oy*56 + xq*4) = ov;
  }
}

// ---------------------------------------------------------------------------
extern "C" void kernel_launch(void* const* d_in, const int* in_sizes, int n_in,
                              void* d_out, int out_size, void* d_ws, size_t ws_size,
                              hipStream_t stream){
  const float* instance_feats = (const float*)d_in[0];
  const float* semantic_feat  = (const float*)d_in[1];
  // d_in[2] semantic_pred: unused by the reference
  const float* rois           = (const float*)d_in[3];
  const int*   roi_labels     = (const int*)d_in[4];
  const float* W_sem = (const float*)d_in[5];
  const float* b_sem = (const float*)d_in[6];
  const float* W_inst= (const float*)d_in[7];
  const float* b_inst= (const float*)d_in[8];
  const float* W_det = (const float*)d_in[9];
  const float* b_det = (const float*)d_in[10];
  const float* W_fc1 = (const float*)d_in[11];
  const float* b_fc1 = (const float*)d_in[12];
  const float* W_fc2 = (const float*)d_in[13];
  const float* b_fc2 = (const float*)d_in[14];
  const float* W_fc3 = (const float*)d_in[15];
  const float* b_fc3 = (const float*)d_in[16];
  const float* W_fuse= (const float*)d_in[17];
  const float* b_fuse= (const float*)d_in[18];

  float* out0 = (float*)d_out;                      // instance_preds (192*784)
  float* out1 = out0 + (size_t)N_INST*HW;           // detail_preds   (192*784)
  float* out2 = out0 + (size_t)2*N_INST*HW;         // relu(up)       (192*256*56*56)

  // workspace layout (bytes): sem_t bf16 | X0 bf16 | X1 bf16 (refined aliases X1) | points
  char* ws = (char*)d_ws;
  unsigned short* sem_t  = (unsigned short*)ws;                  //  62,259,200 B
  unsigned short* X0     = (unsigned short*)(ws + 62259200);     //  77,070,336 B
  unsigned short* X1     = (unsigned short*)(ws + 139329536);    //  77,070,336 B
  int*            points = (int*)(ws + 216399872);               //     301,056 B
  unsigned short* refined = X1;  // X1 is dead after the fuse layer reads it

  k_preds  <<<N_INST, 256, 0, stream>>>(instance_feats, roi_labels, W_inst, b_inst, W_det, b_det, out0, out1);
  k_topk   <<<N_INST, 256, 0, stream>>>(out0, points);
  k_sem    <<<dim3(2*SEM_HW/128, 4), 256, 0, stream>>>(semantic_feat, W_sem, b_sem, sem_t);
  k_sample <<<NROWS/4, 256, 0, stream>>>(sem_t, instance_feats, rois, points, X0, X1);
  k_mlp    <<<dim3(NROWS/128, 4), 256, 0, stream>>>(X0, W_fc1, b_fc1, X1, 1);
  k_mlp    <<<dim3(NROWS/128, 4), 256, 0, stream>>>(X1, W_fc2, b_fc2, X0, 1);
  k_mlp    <<<dim3(NROWS/128, 4), 256, 0, stream>>>(X0, W_fc3, b_fc3, X1, 1);
  k_mlp    <<<dim3(NROWS/128, 4), 256, 0, stream>>>(X1, W_fuse, b_fuse, X0, 0);
  k_refinit<<<2048, 256, 0, stream>>>(instance_feats, refined);
  k_scatter<<<N_INST, 256, 0, stream>>>(X0, points, refined);
  k_upsample<<<2048, 256, 0, stream>>>(refined, out2);
}